// Round 3
// baseline (899.159 us; speedup 1.0000x reference)
//
#include <hip/hip_runtime.h>
#include <hip/hip_bf16.h>

#define D 128
#define LN_EPS 1e-12f

// ---------------------------------------------------------------------------
// Kernel 1: fused 4-table embedding gather + LayerNorm.
// 2 nodes per wave: lanes [s*32 .. s*32+31] own node s, float4 per lane.
// ---------------------------------------------------------------------------
__global__ __launch_bounds__(256) void embed_ln_kernel(
    const int* __restrict__ x,
    const float* __restrict__ syn, const float* __restrict__ lem,
    const float* __restrict__ pos, const float* __restrict__ sen,
    const float* __restrict__ g, const float* __restrict__ b,
    float* __restrict__ h0, int n) {
  int lane = threadIdx.x & 63;
  int q = lane & 31, s = lane >> 5;
  int node = blockIdx.x * 8 + (threadIdx.x >> 6) * 2 + s;
  if (node >= n) return;
  int4 xi = ((const int4*)x)[node];  // columns [syn, pos, sen, lem]
  float4 v0 = ((const float4*)(syn + (size_t)xi.x * D))[q];
  float4 v1 = ((const float4*)(pos + (size_t)xi.y * D))[q];
  float4 v2 = ((const float4*)(sen + (size_t)xi.z * D))[q];
  float4 v3 = ((const float4*)(lem + (size_t)xi.w * D))[q];
  float4 hs;
  hs.x = v0.x + v1.x + v2.x + v3.x;
  hs.y = v0.y + v1.y + v2.y + v3.y;
  hs.z = v0.z + v1.z + v2.z + v3.z;
  hs.w = v0.w + v1.w + v2.w + v3.w;
  float sum = hs.x + hs.y + hs.z + hs.w;
#pragma unroll
  for (int off = 16; off; off >>= 1) sum += __shfl_xor(sum, off);
  float mu = sum * (1.0f / 128.0f);
  float4 d;
  d.x = hs.x - mu; d.y = hs.y - mu; d.z = hs.z - mu; d.w = hs.w - mu;
  float sq = d.x * d.x + d.y * d.y + d.z * d.z + d.w * d.w;
#pragma unroll
  for (int off = 16; off; off >>= 1) sq += __shfl_xor(sq, off);
  float rstd = rsqrtf(sq * (1.0f / 128.0f) + LN_EPS);
  float4 gg = ((const float4*)g)[q];
  float4 bb = ((const float4*)b)[q];
  float4 o;
  o.x = d.x * rstd * gg.x + bb.x;
  o.y = d.y * rstd * gg.y + bb.y;
  o.z = d.z * rstd * gg.z + bb.z;
  o.w = d.w * rstd * gg.w + bb.w;
  ((float4*)(h0 + (size_t)node * D))[q] = o;
}

// ---------------------------------------------------------------------------
// CSR build: histogram of dst, block-scan to row_ptr, bucket fill of src ids.
// ---------------------------------------------------------------------------
__global__ __launch_bounds__(256) void hist_kernel(const int* __restrict__ dst,
                                                   int* __restrict__ counts,
                                                   int nEdges) {
  int e = blockIdx.x * 256 + threadIdx.x;
  if (e < nEdges) atomicAdd(&counts[dst[e]], 1);
}

__global__ __launch_bounds__(1024) void scan_kernel(const int* __restrict__ counts,
                                                    int* __restrict__ row_ptr,
                                                    int n) {
  __shared__ int sums[1024];
  int t = threadIdx.x;
  int CH = (n + 1023) >> 10;
  int beg = t * CH;
  int end = min(beg + CH, n);
  int s = 0;
  for (int i = beg; i < end; ++i) s += counts[i];
  sums[t] = s;
  __syncthreads();
  for (int off = 1; off < 1024; off <<= 1) {
    int u = (t >= off) ? sums[t - off] : 0;
    __syncthreads();
    sums[t] += u;
    __syncthreads();
  }
  int run = sums[t] - s;  // exclusive prefix of this chunk
  for (int i = beg; i < end; ++i) {
    row_ptr[i] = run;
    run += counts[i];
  }
  if (t == 1023) row_ptr[n] = sums[1023];
}

__global__ __launch_bounds__(256) void fill_kernel(const int* __restrict__ src,
                                                   const int* __restrict__ dst,
                                                   const int* __restrict__ row_ptr,
                                                   int* __restrict__ cursor,
                                                   int* __restrict__ adj,
                                                   int nEdges) {
  int e = blockIdx.x * 256 + threadIdx.x;
  if (e >= nEdges) return;
  int d = dst[e];
  int p = atomicAdd(&cursor[d], 1);
  adj[row_ptr[d] + p] = src[e];
}

// ---------------------------------------------------------------------------
// Gather-based mean aggregation: one wave per node; lanes split into two
// 32-lane streams (s = lane>>5), each stream covers alternate neighbors with
// float4/lane row reads, unroll 4 (8 row-loads in flight per wave).
// ---------------------------------------------------------------------------
__global__ __launch_bounds__(256) void gather_agg_kernel(
    const int* __restrict__ row_ptr, const int* __restrict__ adj,
    const float* __restrict__ h, float* __restrict__ agg, int n) {
  int node = blockIdx.x * 4 + (threadIdx.x >> 6);
  if (node >= n) return;
  int lane = threadIdx.x & 63;
  int q = lane & 31, s = lane >> 5;
  int beg = row_ptr[node], end = row_ptr[node + 1];
  int count = end - beg;
  float4 acc = {0.f, 0.f, 0.f, 0.f};
  int end8 = beg + (count & ~7);
  for (int base = beg; base < end8; base += 8) {
    int i = base + s;
    int e0 = adj[i], e1 = adj[i + 2], e2 = adj[i + 4], e3 = adj[i + 6];
    float4 v0 = ((const float4*)(h + (size_t)e0 * D))[q];
    float4 v1 = ((const float4*)(h + (size_t)e1 * D))[q];
    float4 v2 = ((const float4*)(h + (size_t)e2 * D))[q];
    float4 v3 = ((const float4*)(h + (size_t)e3 * D))[q];
    acc.x += v0.x + v1.x + v2.x + v3.x;
    acc.y += v0.y + v1.y + v2.y + v3.y;
    acc.z += v0.z + v1.z + v2.z + v3.z;
    acc.w += v0.w + v1.w + v2.w + v3.w;
  }
  for (int i = end8 + s; i < end; i += 2) {
    int e = adj[i];
    float4 v = ((const float4*)(h + (size_t)e * D))[q];
    acc.x += v.x; acc.y += v.y; acc.z += v.z; acc.w += v.w;
  }
  // combine the two streams (xor 32 swaps halves)
  acc.x += __shfl_xor(acc.x, 32);
  acc.y += __shfl_xor(acc.y, 32);
  acc.z += __shfl_xor(acc.z, 32);
  acc.w += __shfl_xor(acc.w, 32);
  if (s == 0) {
    float inv = 1.0f / fmaxf((float)count, 1.0f);
    float4 o;
    o.x = acc.x * inv; o.y = acc.y * inv; o.z = acc.z * inv; o.w = acc.w * inv;
    ((float4*)(agg + (size_t)node * D))[q] = o;
  }
}

// ---------------------------------------------------------------------------
// SAGE linear layer as register-tiled fp32 GEMM.
//   out[i][j] = bl[j] + agg[i]·Wl[j] + hin[i]·Wr[j]   (+ optional ReLU)
// Tile: 32 nodes x 128 cols per 256-thread block.  A = (agg row ‖ hin row)
// staged in LDS (32x256 fp32 = 32 KB).  Thread (ng=tid>>5, cg=tid&31)
// computes nodes ng*4..+3, cols cg*4..+3 -> 16 fp32 accumulators.
// LDS reads are 2-row broadcast per wave (conflict-free); W streamed from L2.
// ---------------------------------------------------------------------------
#define TN 32
__global__ __launch_bounds__(256) void sage_layer_kernel(
    const float* __restrict__ agg, const float* __restrict__ hin,
    const float* __restrict__ Wl, const float* __restrict__ bl,
    const float* __restrict__ Wr,
    float* __restrict__ out, int n, int doRelu) {
  __shared__ float A[TN][2 * D];  // 32 KB
  int tid = threadIdx.x;
  int base = blockIdx.x * TN;
  // cooperative A-tile load: 32 rows x 64 float4
  for (int f = tid; f < TN * 64; f += 256) {
    int r = f >> 6, c4 = f & 63;
    int node = base + r;
    if (node >= n) node = n - 1;  // clamp: row n-1 is in this (last) block
    float4 v = (c4 < 32) ? ((const float4*)(agg + (size_t)node * D))[c4]
                         : ((const float4*)(hin + (size_t)node * D))[c4 - 32];
    ((float4*)A[r])[c4] = v;
  }
  __syncthreads();

  int cg = tid & 31, ng = tid >> 5;
  int j0 = cg * 4;
  const float4* w0p = (const float4*)(Wl + (size_t)(j0 + 0) * D);
  const float4* w1p = (const float4*)(Wl + (size_t)(j0 + 1) * D);
  const float4* w2p = (const float4*)(Wl + (size_t)(j0 + 2) * D);
  const float4* w3p = (const float4*)(Wl + (size_t)(j0 + 3) * D);
  float4 acc[4];
#pragma unroll
  for (int r = 0; r < 4; ++r) acc[r] = make_float4(0.f, 0.f, 0.f, 0.f);

#pragma unroll 2
  for (int k4 = 0; k4 < 32; ++k4) {
    float4 w0 = w0p[k4], w1 = w1p[k4], w2 = w2p[k4], w3 = w3p[k4];
#pragma unroll
    for (int r = 0; r < 4; ++r) {
      float4 a = ((const float4*)A[ng * 4 + r])[k4];
      acc[r].x += a.x * w0.x + a.y * w0.y + a.z * w0.z + a.w * w0.w;
      acc[r].y += a.x * w1.x + a.y * w1.y + a.z * w1.z + a.w * w1.w;
      acc[r].z += a.x * w2.x + a.y * w2.y + a.z * w2.z + a.w * w2.w;
      acc[r].w += a.x * w3.x + a.y * w3.y + a.z * w3.z + a.w * w3.w;
    }
  }
  w0p = (const float4*)(Wr + (size_t)(j0 + 0) * D);
  w1p = (const float4*)(Wr + (size_t)(j0 + 1) * D);
  w2p = (const float4*)(Wr + (size_t)(j0 + 2) * D);
  w3p = (const float4*)(Wr + (size_t)(j0 + 3) * D);
#pragma unroll 2
  for (int k4 = 0; k4 < 32; ++k4) {
    float4 w0 = w0p[k4], w1 = w1p[k4], w2 = w2p[k4], w3 = w3p[k4];
#pragma unroll
    for (int r = 0; r < 4; ++r) {
      float4 a = ((const float4*)A[ng * 4 + r])[k4 + 32];
      acc[r].x += a.x * w0.x + a.y * w0.y + a.z * w0.z + a.w * w0.w;
      acc[r].y += a.x * w1.x + a.y * w1.y + a.z * w1.z + a.w * w1.w;
      acc[r].z += a.x * w2.x + a.y * w2.y + a.z * w2.z + a.w * w2.w;
      acc[r].w += a.x * w3.x + a.y * w3.y + a.z * w3.z + a.w * w3.w;
    }
  }

  float4 bias = ((const float4*)bl)[cg];
#pragma unroll
  for (int r = 0; r < 4; ++r) {
    int node = base + ng * 4 + r;
    if (node < n) {
      float4 v;
      v.x = acc[r].x + bias.x;
      v.y = acc[r].y + bias.y;
      v.z = acc[r].z + bias.z;
      v.w = acc[r].w + bias.w;
      if (doRelu) {
        v.x = fmaxf(v.x, 0.f); v.y = fmaxf(v.y, 0.f);
        v.z = fmaxf(v.z, 0.f); v.w = fmaxf(v.w, 0.f);
      }
      ((float4*)(out + (size_t)node * D))[cg] = v;
    }
  }
}

// ---------------------------------------------------------------------------
extern "C" void kernel_launch(void* const* d_in, const int* in_sizes, int n_in,
                              void* d_out, int out_size, void* d_ws,
                              size_t ws_size, hipStream_t stream) {
  const int* x = (const int*)d_in[0];
  const int* edge = (const int*)d_in[1];
  const float* syn = (const float*)d_in[2];
  const float* lem = (const float*)d_in[3];
  const float* pos = (const float*)d_in[4];
  const float* sen = (const float*)d_in[5];
  const float* ln_g = (const float*)d_in[6];
  const float* ln_b = (const float*)d_in[7];
  const float* Wl0 = (const float*)d_in[8];
  const float* bl0 = (const float*)d_in[9];
  const float* Wr0 = (const float*)d_in[10];
  const float* Wl1 = (const float*)d_in[11];
  const float* bl1 = (const float*)d_in[12];
  const float* Wr1 = (const float*)d_in[13];

  int n = in_sizes[0] / 4;
  int E = in_sizes[1] / 2;
  const int* srcI = edge;
  const int* dstI = edge + E;
  float* outp = (float*)d_out;

  size_t rowElems = (size_t)n * D;
  // Workspace layout: h0 | hmid | agg | row_ptr[n+1] | counts[n] | cursor[n] | adj[E]
  size_t intElems = (size_t)(3 * n + 1) + (size_t)E;
  size_t needFull = (3 * rowElems + intElems) * sizeof(float);

  float* h0;
  float* hmid;
  float* agg;
  if (ws_size >= needFull) {
    h0 = (float*)d_ws;
    hmid = h0 + rowElems;
    agg = hmid + rowElems;
  } else {
    // tight-workspace fallback: stage layer-0 output in d_out (safe: layer-1
    // sage kernel stages its block's rows in LDS before overwriting them)
    h0 = (float*)d_ws;
    agg = h0 + rowElems;
    hmid = outp;
  }
  int* row_ptr = (int*)(agg + rowElems);
  int* counts = row_ptr + (n + 1);
  int* cursor = counts + n;
  int* adj = cursor + n;

  hipMemsetAsync(counts, 0, 2 * (size_t)n * sizeof(int), stream);

  embed_ln_kernel<<<(n + 7) / 8, 256, 0, stream>>>(x, syn, lem, pos, sen, ln_g,
                                                   ln_b, h0, n);

  int eBlocks = (E + 255) / 256;
  hist_kernel<<<eBlocks, 256, 0, stream>>>(dstI, counts, E);
  scan_kernel<<<1, 1024, 0, stream>>>(counts, row_ptr, n);
  fill_kernel<<<eBlocks, 256, 0, stream>>>(srcI, dstI, row_ptr, cursor, adj, E);

  int gBlocks = (n + 3) / 4;
  int lBlocks = (n + TN - 1) / TN;

  gather_agg_kernel<<<gBlocks, 256, 0, stream>>>(row_ptr, adj, h0, agg, n);
  sage_layer_kernel<<<lBlocks, 256, 0, stream>>>(agg, h0, Wl0, bl0, Wr0, hmid,
                                                 n, 1);
  gather_agg_kernel<<<gBlocks, 256, 0, stream>>>(row_ptr, adj, hmid, agg, n);
  sage_layer_kernel<<<lBlocks, 256, 0, stream>>>(agg, hmid, Wl1, bl1, Wr1, outp,
                                                 n, 0);
}

// Round 4
// 666.188 us; speedup vs baseline: 1.3497x; 1.3497x over previous
//
#include <hip/hip_runtime.h>
#include <hip/hip_bf16.h>

#define D 128
#define LN_EPS 1e-12f

typedef unsigned int uint;
typedef unsigned short ushort_t;

__device__ inline ushort_t f2bf(float f) {  // RNE fp32 -> bf16
  uint u = __float_as_uint(f);
  u += 0x7fffu + ((u >> 16) & 1u);
  return (ushort_t)(u >> 16);
}
__device__ inline uint pack_bf16(float a, float b) {
  return (uint)f2bf(a) | ((uint)f2bf(b) << 16);
}

// ---------------------------------------------------------------------------
// Kernel 1: fused 4-table embedding gather + LayerNorm.
// 2 nodes per wave.  Writes fp32 row (GEMM self-operand) + bf16 row (gather).
// ---------------------------------------------------------------------------
__global__ __launch_bounds__(256) void embed_ln_kernel(
    const int* __restrict__ x,
    const float* __restrict__ syn, const float* __restrict__ lem,
    const float* __restrict__ pos, const float* __restrict__ sen,
    const float* __restrict__ g, const float* __restrict__ b,
    float* __restrict__ h0, ushort_t* __restrict__ h0b, int n) {
  int lane = threadIdx.x & 63;
  int q = lane & 31, s = lane >> 5;
  int node = blockIdx.x * 8 + (threadIdx.x >> 6) * 2 + s;
  if (node >= n) return;
  int4 xi = ((const int4*)x)[node];  // columns [syn, pos, sen, lem]
  float4 v0 = ((const float4*)(syn + (size_t)xi.x * D))[q];
  float4 v1 = ((const float4*)(pos + (size_t)xi.y * D))[q];
  float4 v2 = ((const float4*)(sen + (size_t)xi.z * D))[q];
  float4 v3 = ((const float4*)(lem + (size_t)xi.w * D))[q];
  float4 hs;
  hs.x = v0.x + v1.x + v2.x + v3.x;
  hs.y = v0.y + v1.y + v2.y + v3.y;
  hs.z = v0.z + v1.z + v2.z + v3.z;
  hs.w = v0.w + v1.w + v2.w + v3.w;
  float sum = hs.x + hs.y + hs.z + hs.w;
#pragma unroll
  for (int off = 16; off; off >>= 1) sum += __shfl_xor(sum, off);
  float mu = sum * (1.0f / 128.0f);
  float4 d;
  d.x = hs.x - mu; d.y = hs.y - mu; d.z = hs.z - mu; d.w = hs.w - mu;
  float sq = d.x * d.x + d.y * d.y + d.z * d.z + d.w * d.w;
#pragma unroll
  for (int off = 16; off; off >>= 1) sq += __shfl_xor(sq, off);
  float rstd = rsqrtf(sq * (1.0f / 128.0f) + LN_EPS);
  float4 gg = ((const float4*)g)[q];
  float4 bb = ((const float4*)b)[q];
  float4 o;
  o.x = d.x * rstd * gg.x + bb.x;
  o.y = d.y * rstd * gg.y + bb.y;
  o.z = d.z * rstd * gg.z + bb.z;
  o.w = d.w * rstd * gg.w + bb.w;
  ((float4*)(h0 + (size_t)node * D))[q] = o;
  uint2 p;
  p.x = pack_bf16(o.x, o.y);
  p.y = pack_bf16(o.z, o.w);
  ((uint2*)(h0b + (size_t)node * D))[q] = p;
}

// ---------------------------------------------------------------------------
// CSR build: histogram of dst, block-scan to row_ptr, bucket fill of src ids.
// ---------------------------------------------------------------------------
__global__ __launch_bounds__(256) void hist_kernel(const int* __restrict__ dst,
                                                   int* __restrict__ counts,
                                                   int nEdges) {
  int e = blockIdx.x * 256 + threadIdx.x;
  if (e < nEdges) atomicAdd(&counts[dst[e]], 1);
}

__global__ __launch_bounds__(1024) void scan_kernel(const int* __restrict__ counts,
                                                    int* __restrict__ row_ptr,
                                                    int n) {
  __shared__ int sums[1024];
  int t = threadIdx.x;
  int CH = (n + 1023) >> 10;
  int beg = t * CH;
  int end = min(beg + CH, n);
  int s = 0;
  for (int i = beg; i < end; ++i) s += counts[i];
  sums[t] = s;
  __syncthreads();
  for (int off = 1; off < 1024; off <<= 1) {
    int u = (t >= off) ? sums[t - off] : 0;
    __syncthreads();
    sums[t] += u;
    __syncthreads();
  }
  int run = sums[t] - s;  // exclusive prefix of this chunk
  for (int i = beg; i < end; ++i) {
    row_ptr[i] = run;
    run += counts[i];
  }
  if (t == 1023) row_ptr[n] = sums[1023];
}

__global__ __launch_bounds__(256) void fill_kernel(const int* __restrict__ src,
                                                   const int* __restrict__ dst,
                                                   const int* __restrict__ row_ptr,
                                                   int* __restrict__ cursor,
                                                   int* __restrict__ adj,
                                                   int nEdges) {
  int e = blockIdx.x * 256 + threadIdx.x;
  if (e >= nEdges) return;
  int d = dst[e];
  int p = atomicAdd(&cursor[d], 1);
  adj[row_ptr[d] + p] = src[e];
}

// ---------------------------------------------------------------------------
// bf16 gather mean-aggregation.  One wave per node; 16 lanes cover one 256 B
// bf16 row (uint4 = 8 elems/lane), 4 streams (s = lane>>4) walk alternating
// neighbors, fp32 accumulate, xor-shuffle combine, fp32 agg row written once.
// ---------------------------------------------------------------------------
__global__ __launch_bounds__(256) void gather_bf16_kernel(
    const int* __restrict__ row_ptr, const int* __restrict__ adj,
    const ushort_t* __restrict__ hb, float* __restrict__ agg, int n) {
  int node = blockIdx.x * 4 + (threadIdx.x >> 6);
  if (node >= n) return;
  int lane = threadIdx.x & 63;
  int q = lane & 15, s = lane >> 4;
  int beg = row_ptr[node], end = row_ptr[node + 1];
  int count = end - beg;
  float a0 = 0.f, a1 = 0.f, a2 = 0.f, a3 = 0.f;
  float a4 = 0.f, a5 = 0.f, a6 = 0.f, a7 = 0.f;
  int lim = beg + (count & ~7);
  for (int bb = beg; bb < lim; bb += 8) {
    int e0 = adj[bb + s], e1 = adj[bb + 4 + s];
    uint4 v0 = ((const uint4*)(hb + (size_t)e0 * D))[q];
    uint4 v1 = ((const uint4*)(hb + (size_t)e1 * D))[q];
    a0 += __uint_as_float(v0.x << 16) + __uint_as_float(v1.x << 16);
    a1 += __uint_as_float(v0.x & 0xffff0000u) + __uint_as_float(v1.x & 0xffff0000u);
    a2 += __uint_as_float(v0.y << 16) + __uint_as_float(v1.y << 16);
    a3 += __uint_as_float(v0.y & 0xffff0000u) + __uint_as_float(v1.y & 0xffff0000u);
    a4 += __uint_as_float(v0.z << 16) + __uint_as_float(v1.z << 16);
    a5 += __uint_as_float(v0.z & 0xffff0000u) + __uint_as_float(v1.z & 0xffff0000u);
    a6 += __uint_as_float(v0.w << 16) + __uint_as_float(v1.w << 16);
    a7 += __uint_as_float(v0.w & 0xffff0000u) + __uint_as_float(v1.w & 0xffff0000u);
  }
  for (int i = lim + s; i < end; i += 4) {
    int e0 = adj[i];
    uint4 v0 = ((const uint4*)(hb + (size_t)e0 * D))[q];
    a0 += __uint_as_float(v0.x << 16);
    a1 += __uint_as_float(v0.x & 0xffff0000u);
    a2 += __uint_as_float(v0.y << 16);
    a3 += __uint_as_float(v0.y & 0xffff0000u);
    a4 += __uint_as_float(v0.z << 16);
    a5 += __uint_as_float(v0.z & 0xffff0000u);
    a6 += __uint_as_float(v0.w << 16);
    a7 += __uint_as_float(v0.w & 0xffff0000u);
  }
#pragma unroll
  for (int off = 16; off <= 32; off <<= 1) {
    a0 += __shfl_xor(a0, off); a1 += __shfl_xor(a1, off);
    a2 += __shfl_xor(a2, off); a3 += __shfl_xor(a3, off);
    a4 += __shfl_xor(a4, off); a5 += __shfl_xor(a5, off);
    a6 += __shfl_xor(a6, off); a7 += __shfl_xor(a7, off);
  }
  if (s == 0) {
    float inv = 1.0f / fmaxf((float)count, 1.0f);
    float4 o0 = make_float4(a0 * inv, a1 * inv, a2 * inv, a3 * inv);
    float4 o1 = make_float4(a4 * inv, a5 * inv, a6 * inv, a7 * inv);
    float4* op = (float4*)(agg + (size_t)node * D + q * 8);
    op[0] = o0;
    op[1] = o1;
  }
}

// ---------------------------------------------------------------------------
// SAGE layer as LDS-tiled fp32 GEMM.
//   out[i][j] = bl[j] + agg[i]·Wl[j] + hin[i]·Wr[j]  (+ReLU, + bf16 copy)
// Block: 64 nodes x 128 cols.  k runs 0..255 over [agg|hin] x [Wl|Wr] in 8
// chunks of 32; per chunk the A-tile (64x32) and W-tile (128x32) are staged
// in LDS with coalesced global reads (this fixes R3's per-lane W scatter).
// Thread tile: 8 nodes x 4 strided cols {c,c+32,c+64,c+96} = 32 accs.
// LDS stride 36 floats: 16 B-aligned rows, b128 reads at 4-phase floor.
// ---------------------------------------------------------------------------
__global__ __launch_bounds__(256) void sage_gemm_kernel(
    const float* __restrict__ agg, const float* __restrict__ hin,
    const float* __restrict__ Wl, const float* __restrict__ bl,
    const float* __restrict__ Wr,
    float* __restrict__ out, ushort_t* __restrict__ bfOut, int n, int doRelu) {
  __shared__ float As[64][36];
  __shared__ float Ws[128][36];
  int tid = threadIdx.x;
  int base = blockIdx.x * 64;
  int c = tid & 31, ngrp = tid >> 5;

  float acc[8][4];
#pragma unroll
  for (int r = 0; r < 8; ++r)
#pragma unroll
    for (int m = 0; m < 4; ++m) acc[r][m] = 0.f;

  // staging indices (constant across chunks)
  int arow = tid >> 2, acol = (tid & 3) * 8;
  int wrow = tid >> 1, wcol = (tid & 1) * 16;

  for (int kc = 0; kc < 8; ++kc) {
    const float* Asrc = (kc < 4) ? agg : hin;
    const float* Wsrc = (kc < 4) ? Wl : Wr;
    int kw = (kc & 3) * 32;
    {  // A tile: 64 rows x 32 k
      int node = base + arow;
      if (node >= n) node = n - 1;
      const float4* src = (const float4*)(Asrc + (size_t)node * D + kw + acol);
      float4 x0 = src[0], x1 = src[1];
      *(float4*)&As[arow][acol] = x0;
      *(float4*)&As[arow][acol + 4] = x1;
    }
    {  // W tile: 128 rows x 32 k (row-contiguous global reads)
      const float4* src = (const float4*)(Wsrc + (size_t)wrow * D + kw + wcol);
      float4 w0 = src[0], w1 = src[1], w2 = src[2], w3 = src[3];
      *(float4*)&Ws[wrow][wcol] = w0;
      *(float4*)&Ws[wrow][wcol + 4] = w1;
      *(float4*)&Ws[wrow][wcol + 8] = w2;
      *(float4*)&Ws[wrow][wcol + 12] = w3;
    }
    __syncthreads();
#pragma unroll
    for (int k4 = 0; k4 < 8; ++k4) {
      float4 w0 = *(const float4*)&Ws[c][k4 * 4];
      float4 w1 = *(const float4*)&Ws[c + 32][k4 * 4];
      float4 w2 = *(const float4*)&Ws[c + 64][k4 * 4];
      float4 w3 = *(const float4*)&Ws[c + 96][k4 * 4];
#pragma unroll
      for (int r = 0; r < 8; ++r) {
        float4 a = *(const float4*)&As[ngrp * 8 + r][k4 * 4];
        acc[r][0] += a.x * w0.x + a.y * w0.y + a.z * w0.z + a.w * w0.w;
        acc[r][1] += a.x * w1.x + a.y * w1.y + a.z * w1.z + a.w * w1.w;
        acc[r][2] += a.x * w2.x + a.y * w2.y + a.z * w2.z + a.w * w2.w;
        acc[r][3] += a.x * w3.x + a.y * w3.y + a.z * w3.z + a.w * w3.w;
      }
    }
    __syncthreads();
  }

  float b0 = bl[c], b1 = bl[c + 32], b2 = bl[c + 64], b3 = bl[c + 96];
#pragma unroll
  for (int r = 0; r < 8; ++r) {
    int node = base + ngrp * 8 + r;
    if (node >= n) continue;
    float v0 = acc[r][0] + b0;
    float v1 = acc[r][1] + b1;
    float v2 = acc[r][2] + b2;
    float v3 = acc[r][3] + b3;
    if (doRelu) {
      v0 = fmaxf(v0, 0.f); v1 = fmaxf(v1, 0.f);
      v2 = fmaxf(v2, 0.f); v3 = fmaxf(v3, 0.f);
    }
    float* op = out + (size_t)node * D;
    op[c] = v0;
    op[c + 32] = v1;
    op[c + 64] = v2;
    op[c + 96] = v3;
    if (bfOut) {
      ushort_t* bp = bfOut + (size_t)node * D;
      bp[c] = f2bf(v0);
      bp[c + 32] = f2bf(v1);
      bp[c + 64] = f2bf(v2);
      bp[c + 96] = f2bf(v3);
    }
  }
}

// ---------------------------------------------------------------------------
extern "C" void kernel_launch(void* const* d_in, const int* in_sizes, int n_in,
                              void* d_out, int out_size, void* d_ws,
                              size_t ws_size, hipStream_t stream) {
  const int* x = (const int*)d_in[0];
  const int* edge = (const int*)d_in[1];
  const float* syn = (const float*)d_in[2];
  const float* lem = (const float*)d_in[3];
  const float* pos = (const float*)d_in[4];
  const float* sen = (const float*)d_in[5];
  const float* ln_g = (const float*)d_in[6];
  const float* ln_b = (const float*)d_in[7];
  const float* Wl0 = (const float*)d_in[8];
  const float* bl0 = (const float*)d_in[9];
  const float* Wr0 = (const float*)d_in[10];
  const float* Wl1 = (const float*)d_in[11];
  const float* bl1 = (const float*)d_in[12];
  const float* Wr1 = (const float*)d_in[13];

  int n = in_sizes[0] / 4;
  int E = in_sizes[1] / 2;
  const int* srcI = edge;
  const int* dstI = edge + E;
  float* outp = (float*)d_out;

  size_t rowElems = (size_t)n * D;
  // Layout: h0[rowE] | hmid[rowE] | agg[rowE] | h0b[rowE bf16] |
  //         hmidb[rowE bf16] | row_ptr[n+1] | counts[n] | cursor[n] | adj[E]
  size_t intElems = (size_t)(3 * n + 1) + (size_t)E;
  size_t needFull = (3 * rowElems + rowElems /*2x bf16*/) * sizeof(float) +
                    intElems * sizeof(int);

  float* h0 = (float*)d_ws;
  float* hmid;
  float* agg;
  if (ws_size >= needFull) {
    hmid = h0 + rowElems;
    agg = hmid + rowElems;
  } else {
    // tight-workspace fallback: hmid lives in d_out (safe: layer-2 GEMM
    // reads only its own block's rows, all before its epilogue writes them)
    hmid = outp;
    agg = h0 + rowElems;
  }
  ushort_t* h0b = (ushort_t*)(agg + rowElems);
  ushort_t* hmidb = h0b + rowElems;
  int* row_ptr = (int*)(hmidb + rowElems);
  int* counts = row_ptr + (n + 1);
  int* cursor = counts + n;
  int* adj = cursor + n;

  hipMemsetAsync(counts, 0, 2 * (size_t)n * sizeof(int), stream);

  embed_ln_kernel<<<(n + 7) / 8, 256, 0, stream>>>(x, syn, lem, pos, sen, ln_g,
                                                   ln_b, h0, h0b, n);

  int eBlocks = (E + 255) / 256;
  hist_kernel<<<eBlocks, 256, 0, stream>>>(dstI, counts, E);
  scan_kernel<<<1, 1024, 0, stream>>>(counts, row_ptr, n);
  fill_kernel<<<eBlocks, 256, 0, stream>>>(srcI, dstI, row_ptr, cursor, adj, E);

  int gBlocks = (n + 3) / 4;
  int sBlocks = (n + 63) / 64;

  gather_bf16_kernel<<<gBlocks, 256, 0, stream>>>(row_ptr, adj, h0b, agg, n);
  sage_gemm_kernel<<<sBlocks, 256, 0, stream>>>(agg, h0, Wl0, bl0, Wr0, hmid,
                                                hmidb, n, 1);
  gather_bf16_kernel<<<gBlocks, 256, 0, stream>>>(row_ptr, adj, hmidb, agg, n);
  sage_gemm_kernel<<<sBlocks, 256, 0, stream>>>(agg, hmid, Wl1, bl1, Wr1, outp,
                                                nullptr, n, 0);
}